// Round 1
// 1758.459 us; speedup vs baseline: 1.2407x; 1.2407x over previous
//
#include <hip/hip_runtime.h>
#include <math.h>

// Problem constants
#define B_    32
#define CIN   4
#define SLEN  2048
#define NF    256
#define HD    256          // LSTM hidden per direction
#define SP    341          // post conv+pool sequence length
#define RTOT  (B_*SP)      // 10912 rows
#define NH_   8
#define DH_   64
#define GRP   4            // batches per attention group
#define PSTR  344          // padded P row stride (16B-aligned)
#define HS    (SP*HD)      // 87296: per-dir h elems

typedef __attribute__((ext_vector_type(8))) short short8;
typedef __attribute__((ext_vector_type(4))) float floatx4;
typedef __attribute__((ext_vector_type(4))) unsigned short ushortx4;

__device__ __forceinline__ float sigmoidf_(float x) { return 1.0f / (1.0f + expf(-x)); }

__device__ __forceinline__ unsigned short f2bf(float x) {
    unsigned int u = __float_as_uint(x);
    unsigned int r = (u + 0x7FFF + ((u >> 16) & 1)) >> 16;   // RNE
    return (unsigned short)r;
}
__device__ __forceinline__ float bf2f(unsigned short b) {
    return __uint_as_float(((unsigned int)b) << 16);
}

// ---------------------------------------------------------------------------
// Kernel 1: Conv1d(4->256,k13,pad6) + BN(eval) + ReLU + MaxPool1d(6) -> x0[b*341+s][co]
// ---------------------------------------------------------------------------
__global__ __launch_bounds__(256)
void conv_pool_k(const float* __restrict__ in, const float* __restrict__ cw,
                 const float* __restrict__ gamma, const float* __restrict__ beta,
                 float* __restrict__ x0)
{
    const int b  = blockIdx.y;
    const int s0 = blockIdx.x * 16;
    const int co = threadIdx.x;
    __shared__ float ins[CIN][16*6 + 12];
    for (int idx = threadIdx.x; idx < CIN*108; idx += 256) {
        int ci = idx / 108, o = idx % 108;
        int pos = 6*s0 - 6 + o;
        ins[ci][o] = (pos >= 0 && pos < SLEN) ? in[(b*CIN + ci)*SLEN + pos] : 0.0f;
    }
    float wreg[52];
    {
        const float4* wp = (const float4*)(cw + co*52);
        #pragma unroll
        for (int j4 = 0; j4 < 13; ++j4) {
            float4 w4 = wp[j4];
            wreg[j4*4+0]=w4.x; wreg[j4*4+1]=w4.y; wreg[j4*4+2]=w4.z; wreg[j4*4+3]=w4.w;
        }
    }
    const float scale = gamma[co] * (1.0f / sqrtf(1.0f + 1e-5f));
    const float shift = beta[co];
    __syncthreads();
    for (int si = 0; si < 16; ++si) {
        int s = s0 + si;
        if (s >= SP) break;
        float win[CIN][18];
        #pragma unroll
        for (int ci = 0; ci < CIN; ++ci)
            #pragma unroll
            for (int o = 0; o < 18; ++o)
                win[ci][o] = ins[ci][6*si + o];
        float m = -1e30f;
        #pragma unroll
        for (int p6 = 0; p6 < 6; ++p6) {
            float acc = 0.0f;
            #pragma unroll
            for (int ci = 0; ci < CIN; ++ci)
                #pragma unroll
                for (int kk = 0; kk < 13; ++kk)
                    acc += win[ci][p6+kk] * wreg[ci*13+kk];
            float val = acc * scale + shift;
            val = fmaxf(val, 0.0f);
            m = fmaxf(m, val);
        }
        x0[(size_t)(b*SP + s)*NF + co] = m;
    }
}

// ---------------------------------------------------------------------------
// Kernel 2: vectorized fp32 -> bf16 hi/lo split pack (4 elems/thread)
// ---------------------------------------------------------------------------
__global__ __launch_bounds__(256)
void pack4_k(const float* __restrict__ W, unsigned short* __restrict__ hi,
             unsigned short* __restrict__ lo, int n4)
{
    int i = blockIdx.x * 256 + threadIdx.x;
    if (i >= n4) return;
    float4 x = *((const float4*)W + i);
    float v[4] = {x.x, x.y, x.z, x.w};
    ushortx4 h, l;
    #pragma unroll
    for (int e = 0; e < 4; ++e) {
        unsigned short hb = f2bf(v[e]);
        h[e] = hb;
        l[e] = f2bf(v[e] - bf2f(hb));
    }
    *((ushortx4*)hi + i) = h;
    *((ushortx4*)lo + i) = l;
}

// ---------------------------------------------------------------------------
// Kernel 3: split-bf16 MFMA GEMM  C[M,N] = act(A[M,K] @ Bw[N,K]^T + bias[N])
// A,Bw pre-packed as bf16 hi/lo.  acc += Ahi*Bhi + Ahi*Blo + Alo*Bhi (fp32 acc,
// lo*lo dropped ~2^-18 rel).  Tile 128x128, 4 waves (2x2 of 64x64), K-step 32.
// Fragment layout identical to lstm_step_mfma_k (verified): A-frag m=lane&15,
// k=(lane>>4)*8+e; B-frag n=lane&15 same k; D: n=lane&15, m=(lane>>4)*4+r.
// LDS rows padded to 40 ushorts (80B): 16B-aligned b128 ops, ~2-way conflicts.
// ---------------------------------------------------------------------------
template<int RELU>
__global__ __launch_bounds__(256)
void gemm_bf_k(const unsigned short* __restrict__ Ahi, const unsigned short* __restrict__ Alo,
               const unsigned short* __restrict__ Bhi, const unsigned short* __restrict__ Blo,
               const float* __restrict__ bias, float* __restrict__ C,
               int M, int N, int K)
{
    const int n0 = blockIdx.x * 128;
    const int m0 = blockIdx.y * 128;
    const int tid = threadIdx.x;
    const int lane = tid & 63;
    const int w = tid >> 6;
    const int wm = w >> 1, wn = w & 1;          // wave 2x2 over the 128x128 tile
    const int ln15 = lane & 15, lq = lane >> 4;

    __shared__ unsigned short AsH[128][40];
    __shared__ unsigned short AsL[128][40];
    __shared__ unsigned short BsH[128][40];
    __shared__ unsigned short BsL[128][40];

    floatx4 acc[4][4];
    #pragma unroll
    for (int i = 0; i < 4; ++i)
        #pragma unroll
        for (int j = 0; j < 4; ++j) acc[i][j] = (floatx4){0.f, 0.f, 0.f, 0.f};

    // staging map: chunk c in {tid, tid+256}; row = c>>2 (0..127), col = (c&3)*8
    const int srow = tid >> 2;              // 0..63
    const int scol = (tid & 3) * 8;
    int ra0 = m0 + srow;      if (ra0 >= M) ra0 = M - 1;
    int ra1 = m0 + srow + 64; if (ra1 >= M) ra1 = M - 1;
    const int rb0 = n0 + srow;
    const int rb1 = n0 + srow + 64;

    for (int k0 = 0; k0 < K; k0 += 32) {
        const size_t aoff0 = (size_t)ra0*K + k0 + scol;
        const size_t aoff1 = (size_t)ra1*K + k0 + scol;
        const size_t boff0 = (size_t)rb0*K + k0 + scol;
        const size_t boff1 = (size_t)rb1*K + k0 + scol;
        short8 ah0 = *(const short8*)(Ahi + aoff0);
        short8 ah1 = *(const short8*)(Ahi + aoff1);
        short8 al0 = *(const short8*)(Alo + aoff0);
        short8 al1 = *(const short8*)(Alo + aoff1);
        short8 bh0 = *(const short8*)(Bhi + boff0);
        short8 bh1 = *(const short8*)(Bhi + boff1);
        short8 bl0 = *(const short8*)(Blo + boff0);
        short8 bl1 = *(const short8*)(Blo + boff1);
        *(short8*)&AsH[srow     ][scol] = ah0;
        *(short8*)&AsH[srow + 64][scol] = ah1;
        *(short8*)&AsL[srow     ][scol] = al0;
        *(short8*)&AsL[srow + 64][scol] = al1;
        *(short8*)&BsH[srow     ][scol] = bh0;
        *(short8*)&BsH[srow + 64][scol] = bh1;
        *(short8*)&BsL[srow     ][scol] = bl0;
        *(short8*)&BsL[srow + 64][scol] = bl1;
        __syncthreads();

        short8 fa_h[4], fa_l[4], fb_h[4], fb_l[4];
        #pragma unroll
        for (int mt = 0; mt < 4; ++mt) {
            fa_h[mt] = *(const short8*)&AsH[wm*64 + mt*16 + ln15][lq*8];
            fa_l[mt] = *(const short8*)&AsL[wm*64 + mt*16 + ln15][lq*8];
        }
        #pragma unroll
        for (int nt = 0; nt < 4; ++nt) {
            fb_h[nt] = *(const short8*)&BsH[wn*64 + nt*16 + ln15][lq*8];
            fb_l[nt] = *(const short8*)&BsL[wn*64 + nt*16 + ln15][lq*8];
        }
        #pragma unroll
        for (int mt = 0; mt < 4; ++mt)
            #pragma unroll
            for (int nt = 0; nt < 4; ++nt) {
                acc[mt][nt] = __builtin_amdgcn_mfma_f32_16x16x32_bf16(fa_l[mt], fb_h[nt], acc[mt][nt], 0, 0, 0);
                acc[mt][nt] = __builtin_amdgcn_mfma_f32_16x16x32_bf16(fa_h[mt], fb_l[nt], acc[mt][nt], 0, 0, 0);
                acc[mt][nt] = __builtin_amdgcn_mfma_f32_16x16x32_bf16(fa_h[mt], fb_h[nt], acc[mt][nt], 0, 0, 0);
            }
        __syncthreads();
    }

    // epilogue: D layout n=lane&15 (col), m=(lane>>4)*4+r (row)
    #pragma unroll
    for (int nt = 0; nt < 4; ++nt) {
        const int n = n0 + wn*64 + nt*16 + ln15;
        const float bv = bias[n];
        #pragma unroll
        for (int mt = 0; mt < 4; ++mt) {
            const int mbase = m0 + wm*64 + mt*16 + lq*4;
            #pragma unroll
            for (int r = 0; r < 4; ++r) {
                int m = mbase + r;
                if (m < M) {
                    float val = acc[mt][nt][r] + bv;
                    if (RELU) val = fmaxf(val, 0.0f);
                    C[(size_t)m*N + n] = val;
                }
            }
        }
    }
}

// ---------------------------------------------------------------------------
// Kernel 3b: one LSTM step via split-bf16 MFMA (unchanged from prior session).
// ---------------------------------------------------------------------------
__global__ __launch_bounds__(256)
void lstm_step_mfma_k(const float* __restrict__ G,              // [32*341][2048]
                      const unsigned short* __restrict__ Whi,   // [2][1024][256]
                      const unsigned short* __restrict__ Wlo,
                      const float* __restrict__ h_in,           // [2][341][256] fp32
                      float* __restrict__ h_out,
                      float* __restrict__ c_st,                 // [2][341][256]
                      float* __restrict__ x_out,                // [32*341][512]
                      int s)
{
    const int j0 = blockIdx.x * 32;
    const int m0 = blockIdx.y * 32;
    const int d  = blockIdx.z;
    const int t_in = d ? (B_ - 1 - s) : s;
    const int tid = threadIdx.x;
    const int w = tid >> 6, lane = tid & 63;
    const int mhalf = w & 1, gpair = w >> 1;
    const int ln15 = lane & 15, lq = lane >> 4;

    __shared__ float Csh[32][132];

    int am = m0 + mhalf*16 + ln15; if (am > SP-1) am = SP-1;   // A row (clamped)
    const int akoff = lq * 8;
    const float* hA = h_in + (size_t)d*HS + (size_t)am*HD;

    const unsigned short* WhiD = Whi + (size_t)d*1024*256;
    const unsigned short* WloD = Wlo + (size_t)d*1024*256;
    int nrow[4];   // Whh row (output col) per n-subtile: gates {2*gpair,2*gpair+1} x j-halves
    #pragma unroll
    for (int t = 0; t < 4; ++t)
        nrow[t] = (gpair*2 + (t>>1))*256 + j0 + (t&1)*16 + ln15;

    floatx4 acc[4];
    #pragma unroll
    for (int t = 0; t < 4; ++t) acc[t] = (floatx4){0.f, 0.f, 0.f, 0.f};

    #pragma unroll
    for (int kk = 0; kk < 8; ++kk) {
        const int ko = kk*32 + akoff;
        float4 v0 = *(const float4*)(hA + ko);
        float4 v1 = *(const float4*)(hA + ko + 4);
        float vv[8] = {v0.x, v0.y, v0.z, v0.w, v1.x, v1.y, v1.z, v1.w};
        short8 ahi, alo;
        #pragma unroll
        for (int e = 0; e < 8; ++e) {
            unsigned short hb16 = f2bf(vv[e]);
            ahi[e] = (short)hb16;
            alo[e] = (short)f2bf(vv[e] - bf2f(hb16));
        }
        #pragma unroll
        for (int t = 0; t < 4; ++t) {
            short8 bhi = *(const short8*)(WhiD + (size_t)nrow[t]*HD + ko);
            short8 blo = *(const short8*)(WloD + (size_t)nrow[t]*HD + ko);
            acc[t] = __builtin_amdgcn_mfma_f32_16x16x32_bf16(alo, bhi, acc[t], 0, 0, 0);
            acc[t] = __builtin_amdgcn_mfma_f32_16x16x32_bf16(ahi, blo, acc[t], 0, 0, 0);
            acc[t] = __builtin_amdgcn_mfma_f32_16x16x32_bf16(ahi, bhi, acc[t], 0, 0, 0);
        }
    }

    // dump C fragments to LDS (D: col=lane&15, row=lq*4+reg)
    #pragma unroll
    for (int t = 0; t < 4; ++t) {
        int col = gpair*64 + (t>>1)*32 + (t&1)*16 + ln15;
        int rb  = mhalf*16 + lq*4;
        #pragma unroll
        for (int r = 0; r < 4; ++r)
            Csh[rb + r][col] = acc[t][r];
    }
    __syncthreads();

    const int emloc = tid >> 3;           // 0..31 local row
    const int ej4   = (tid & 7) * 4;      // 0..28 local col (x4)
    const int em    = m0 + emloc;
    if (em < SP) {
        size_t gb = ((size_t)t_in*SP + em)*2048 + (size_t)d*1024 + j0 + ej4;
        float4 gi4 = *(const float4*)&G[gb];
        float4 gf4 = *(const float4*)&G[gb + 256];
        float4 gg4 = *(const float4*)&G[gb + 512];
        float4 go4 = *(const float4*)&G[gb + 768];
        size_t cbase = ((size_t)d*SP + em)*HD + j0 + ej4;
        float4 cold = *(float4*)&c_st[cbase];
        float hv[4];
        #pragma unroll
        for (int e = 0; e < 4; ++e) {
            float gi = Csh[emloc][     ej4+e] + (&gi4.x)[e];
            float gf = Csh[emloc][32 + ej4+e] + (&gf4.x)[e];
            float gg = Csh[emloc][64 + ej4+e] + (&gg4.x)[e];
            float go = Csh[emloc][96 + ej4+e] + (&go4.x)[e];
            float cn = sigmoidf_(gf)*(&cold.x)[e] + sigmoidf_(gi)*tanhf(gg);
            (&cold.x)[e] = cn;
            hv[e] = sigmoidf_(go)*tanhf(cn);
        }
        *(float4*)&c_st[cbase] = cold;
        float4 ho; ho.x = hv[0]; ho.y = hv[1]; ho.z = hv[2]; ho.w = hv[3];
        *(float4*)&h_out[cbase] = ho;
        *(float4*)&x_out[((size_t)t_in*SP + em)*512 + d*HD + j0 + ej4] = ho;
    }
}

// ---------------------------------------------------------------------------
// Kernel 4a: scores tile (64x64), RPE analytic.
// ---------------------------------------------------------------------------
__global__ __launch_bounds__(256)
void scores_k(const float* __restrict__ q, const float* __restrict__ k,
              float* __restrict__ P, int g)
{
    const int h = blockIdx.z, bl = blockIdx.y, bg = g*GRP + bl;
    const int q0 = (blockIdx.x / 6) * 64;
    const int k0 = (blockIdx.x % 6) * 64;
    const int tid = threadIdx.x;
    __shared__ float qs[64][68];
    __shared__ float ks[64][68];
    {
        int jr = tid >> 2, c16 = (tid & 3) * 16;
        int qq = q0 + jr; if (qq > SP-1) qq = SP-1;
        int kr = k0 + jr; if (kr > SP-1) kr = SP-1;
        const float* qp = &q[((size_t)bg*SP + qq)*512 + h*64 + c16];
        const float* kp = &k[((size_t)bg*SP + kr)*512 + h*64 + c16];
        #pragma unroll
        for (int u = 0; u < 4; ++u) {
            *(float4*)&qs[jr][c16 + u*4] = *(const float4*)(qp + u*4);
            *(float4*)&ks[jr][c16 + u*4] = *(const float4*)(kp + u*4);
        }
    }
    __syncthreads();
    const int tx = tid & 15, ty = tid >> 4;
    float acc[4][4];
    #pragma unroll
    for (int i = 0; i < 4; ++i)
        #pragma unroll
        for (int j = 0; j < 4; ++j) acc[i][j] = 0.0f;
    for (int d4 = 0; d4 < 64; d4 += 4) {
        float4 a[4], b[4];
        #pragma unroll
        for (int i = 0; i < 4; ++i) a[i] = *(const float4*)&qs[ty + 16*i][d4];
        #pragma unroll
        for (int j = 0; j < 4; ++j) b[j] = *(const float4*)&ks[tx + 16*j][d4];
        #pragma unroll
        for (int i = 0; i < 4; ++i)
            #pragma unroll
            for (int j = 0; j < 4; ++j)
                acc[i][j] += a[i].x*b[j].x + a[i].y*b[j].y + a[i].z*b[j].z + a[i].w*b[j].w;
    }
    #pragma unroll
    for (int i = 0; i < 4; ++i) {
        int qq = q0 + ty + 16*i;
        if (qq >= SP) continue;
        int r0 = 6*qq - 1; if (r0 < 0) r0 = 0;
        int r1 = 6*qq + 7; if (r1 > SLEN-1) r1 = SLEN-1;
        size_t rowb = ((size_t)(h*GRP + bl)*SP + qq) * PSTR;
        #pragma unroll
        for (int j = 0; j < 4; ++j) {
            int kk = k0 + tx + 16*j;
            if (kk >= SP) continue;
            int c0 = 6*kk - 1; if (c0 < 0) c0 = 0;
            int c1 = 6*kk + 7;
            int dd1 = c1 - r0; if (dd1 < 0) dd1 = -dd1;
            int dd2 = r1 - c0; if (dd2 < 0) dd2 = -dd2;
            int den = dd1 > dd2 ? dd1 : dd2;
            P[rowb + kk] = (acc[i][j] * 0.125f) * 2047.0f / (float)den;
        }
    }
}

// ---------------------------------------------------------------------------
// Kernel 4b: row softmax in place.
// ---------------------------------------------------------------------------
__global__ __launch_bounds__(256)
void softmax_k(float* __restrict__ P)
{
    const int tid = threadIdx.x;
    const int row = blockIdx.x * 4 + (tid >> 6);
    const int lane = tid & 63;
    float* rp = P + (size_t)row * PSTR;
    float v[6];
    float m = -1e30f;
    #pragma unroll
    for (int i = 0; i < 6; ++i) {
        int col = lane + 64*i;
        v[i] = (col < SP) ? rp[col] : -1e30f;
        m = fmaxf(m, v[i]);
    }
    #pragma unroll
    for (int o = 1; o < 64; o <<= 1) m = fmaxf(m, __shfl_xor(m, o, 64));
    float s = 0.0f;
    #pragma unroll
    for (int i = 0; i < 6; ++i) {
        v[i] = expf(v[i] - m);
        s += v[i];
    }
    #pragma unroll
    for (int o = 1; o < 64; o <<= 1) s += __shfl_xor(s, o, 64);
    float inv = 1.0f / s;
    #pragma unroll
    for (int i = 0; i < 6; ++i) {
        int col = lane + 64*i;
        if (col < SP) rp[col] = v[i] * inv;
    }
}

// ---------------------------------------------------------------------------
// Kernel 4c: out = relu(P @ V), K=SP in 6x64 chunks.
// ---------------------------------------------------------------------------
__global__ __launch_bounds__(256)
void pv_k(const float* __restrict__ P, const float* __restrict__ v,
          float* __restrict__ cat, int g)
{
    const int h = blockIdx.z, bl = blockIdx.y, bg = g*GRP + bl;
    const int q0 = blockIdx.x * 64;
    const int tid = threadIdx.x;
    __shared__ float ps[64][68];
    __shared__ float vs[64][68];
    const int tx = tid & 15, ty = tid >> 4;
    float acc[4][4];
    #pragma unroll
    for (int i = 0; i < 4; ++i)
        #pragma unroll
        for (int j = 0; j < 4; ++j) acc[i][j] = 0.0f;

    for (int kc = 0; kc < 6; ++kc) {
        const int kk0 = kc * 64;
        {
            int jr = tid >> 2, c16 = (tid & 3) * 16;
            int qq = q0 + jr; if (qq > SP-1) qq = SP-1;
            const float* pp = P + ((size_t)(h*GRP + bl)*SP + qq)*PSTR + kk0 + c16;
            #pragma unroll
            for (int u = 0; u < 4; ++u) {
                float4 w = *(const float4*)(pp + u*4);
                int klb = c16 + u*4;
                float vals[4] = {w.x, w.y, w.z, w.w};
                #pragma unroll
                for (int e = 0; e < 4; ++e)
                    ps[klb + e][jr] = (kk0 + klb + e < SP) ? vals[e] : 0.0f;
            }
        }
        {
            int jr = tid >> 2, c16 = (tid & 3) * 16;
            int kr = kk0 + jr; if (kr > SP-1) kr = SP-1;
            const float* vp = &v[((size_t)bg*SP + kr)*512 + h*64 + c16];
            #pragma unroll
            for (int u = 0; u < 4; ++u)
                *(float4*)&vs[jr][c16 + u*4] = *(const float4*)(vp + u*4);
        }
        __syncthreads();
        for (int kk = 0; kk < 64; ++kk) {
            float4 a4 = *(const float4*)&ps[kk][ty*4];
            float4 b4 = *(const float4*)&vs[kk][tx*4];
            float av[4] = {a4.x, a4.y, a4.z, a4.w};
            float bv[4] = {b4.x, b4.y, b4.z, b4.w};
            #pragma unroll
            for (int i = 0; i < 4; ++i)
                #pragma unroll
                for (int j = 0; j < 4; ++j)
                    acc[i][j] += av[i] * bv[j];
        }
        __syncthreads();
    }
    #pragma unroll
    for (int i = 0; i < 4; ++i) {
        int qq = q0 + ty*4 + i;
        if (qq >= SP) continue;
        float4 r;
        r.x = fmaxf(acc[i][0], 0.0f);
        r.y = fmaxf(acc[i][1], 0.0f);
        r.z = fmaxf(acc[i][2], 0.0f);
        r.w = fmaxf(acc[i][3], 0.0f);
        *(float4*)&cat[((size_t)bg*SP + qq)*512 + h*64 + tx*4] = r;
    }
}

// ---------------------------------------------------------------------------
extern "C" void kernel_launch(void* const* d_in, const int* in_sizes, int n_in,
                              void* d_out, int out_size, void* d_ws, size_t ws_size,
                              hipStream_t stream)
{
    (void)in_sizes; (void)n_in; (void)out_size; (void)ws_size;
    const float* in    = (const float*)d_in[0];
    const float* cw    = (const float*)d_in[1];
    const float* gamma = (const float*)d_in[2];
    const float* beta  = (const float*)d_in[3];
    const float* Wih0  = (const float*)d_in[4];
    const float* Whh0  = (const float*)d_in[5];
    const float* b0    = (const float*)d_in[6];
    const float* Wih1  = (const float*)d_in[7];
    const float* Whh1  = (const float*)d_in[8];
    const float* b1    = (const float*)d_in[9];
    const float* Qw    = (const float*)d_in[10];
    const float* Qb    = (const float*)d_in[11];
    const float* Kw    = (const float*)d_in[12];
    const float* Kb    = (const float*)d_in[13];
    const float* Vw    = (const float*)d_in[14];
    const float* Vb    = (const float*)d_in[15];
    const float* mhw   = (const float*)d_in[16];
    const float* mhb   = (const float*)d_in[17];
    float* out = (float*)d_out;

    // workspace arena (floats). Total 147.36 MB — same map as prior session.
    float* x0 = (float*)d_ws;                                   //  2,793,472 f
    float* G  = x0 + (size_t)RTOT*NF;                           // 22,347,776 f
    float* x1 = G  + (size_t)RTOT*2048;                         //  5,586,944 f
    float* x2 = x1 + (size_t)RTOT*512;                          //  5,586,944 f
    float* hb = x2 + (size_t)RTOT*512;                          //    349,184 f
    float* cb = hb + (size_t)2*2*SP*HD;                         //    174,592 f

    float* qbuf = G;
    float* kbuf = G + (size_t)RTOT*512;
    float* vbuf = G + (size_t)2*RTOT*512;
    float* P    = G + (size_t)3*RTOT*512;
    float* cat  = x1;
    const size_t hsz = (size_t)2*SP*HD;

    // ---- packed-buffer aliases (all inside dead regions at time of use) ----
    // x2 region phase 1 (until gemm1 done): Wih0 pack + x0 pack
    unsigned short* wih0_hi = (unsigned short*)x2;                         // 524,288 ush
    unsigned short* wih0_lo = wih0_hi + (size_t)524288;
    unsigned short* x0_hi   = wih0_lo + (size_t)524288;                    // 2,793,472 ush
    unsigned short* x0_lo   = x0_hi   + (size_t)2793472;                   // ends 3,317,760 f < 5,586,944 f
    // x0 region (after x0 packed): Whh0/Whh1/Wih1 packs
    unsigned short* whh0_hi = (unsigned short*)x0;
    unsigned short* whh0_lo = whh0_hi + (size_t)524288;
    unsigned short* whh1_hi = whh0_lo + (size_t)524288;
    unsigned short* whh1_lo = whh1_hi + (size_t)524288;
    unsigned short* wih1_hi = whh1_lo + (size_t)524288;                    // 1,048,576 ush
    unsigned short* wih1_lo = wih1_hi + (size_t)1048576;                   // ends 2,097,152 f < 2,793,472 f
    // x2 region phase 2 (between scan1 and gemm2): x1 pack (exact fit)
    unsigned short* x1_hi = (unsigned short*)x2;
    unsigned short* x1_lo = x1_hi + (size_t)5586944;
    // x1 region (after x1 packed): x2 pack (exact fit); dead before pv writes cat
    unsigned short* x2_hi = (unsigned short*)x1;
    unsigned short* x2_lo = x2_hi + (size_t)5586944;
    // G tail slack after P (G dead after scan2): Qw/Kw/Vw/mhw packs
    float* gslack = P + (size_t)NH_*GRP*SP*PSTR;                           // 1,833,216 f slack
    unsigned short* qw_hi = (unsigned short*)gslack;
    unsigned short* qw_lo = qw_hi + (size_t)262144;
    unsigned short* kw_hi = qw_lo + (size_t)262144;
    unsigned short* kw_lo = kw_hi + (size_t)262144;
    unsigned short* vw_hi = kw_lo + (size_t)262144;
    unsigned short* vw_lo = vw_hi + (size_t)262144;
    unsigned short* mw_hi = vw_lo + (size_t)262144;
    unsigned short* mw_lo = mw_hi + (size_t)262144;                        // 1,048,576 f used
    // x2 region phase 3 (after x2 packed): cat pack (exact fit)
    unsigned short* cat_hi = (unsigned short*)x2;
    unsigned short* cat_lo = cat_hi + (size_t)5586944;

    #define PACKGRID(n4) dim3(((n4) + 255) / 256)

    // 1. conv+bn+relu+pool -> x0
    conv_pool_k<<<dim3(22, B_), 256, 0, stream>>>(in, cw, gamma, beta, x0);
    // 2. pack Wih0 and x0 (into x2 region)
    pack4_k<<<PACKGRID(131072), 256, 0, stream>>>(Wih0, wih0_hi, wih0_lo, 131072);
    pack4_k<<<PACKGRID(698368), 256, 0, stream>>>(x0, x0_hi, x0_lo, 698368);
    // 3. layer-1 input gates via MFMA: G = x0 @ Wih0^T + b0
    gemm_bf_k<0><<<dim3(16, 86), 256, 0, stream>>>(x0_hi, x0_lo, wih0_hi, wih0_lo, b0, G, RTOT, 2048, 256);
    // 4. pack Whh0/Whh1/Wih1 into x0 region (x0 fp32 dead after step 2)
    pack4_k<<<PACKGRID(131072), 256, 0, stream>>>(Whh0, whh0_hi, whh0_lo, 131072);
    pack4_k<<<PACKGRID(131072), 256, 0, stream>>>(Whh1, whh1_hi, whh1_lo, 131072);
    pack4_k<<<PACKGRID(262144), 256, 0, stream>>>(Wih1, wih1_hi, wih1_lo, 262144);
    // 5. layer-1 scan
    hipMemsetAsync(hb, 0, 2*hsz*sizeof(float), stream);
    hipMemsetAsync(cb, 0, hsz*sizeof(float), stream);
    for (int s = 0; s < B_; ++s) {
        float* hin  = hb + (size_t)(s & 1) * hsz;
        float* hout = hb + (size_t)((s+1) & 1) * hsz;
        lstm_step_mfma_k<<<dim3(8, 11, 2), 256, 0, stream>>>(
            G, whh0_hi, whh0_lo, hin, hout, cb, x1, s);
    }
    // 6. pack x1 (into x2 region; x0p/Wih0p dead after gemm1)
    pack4_k<<<PACKGRID(1396736), 256, 0, stream>>>(x1, x1_hi, x1_lo, 1396736);
    // 7. layer-2 input gates
    gemm_bf_k<0><<<dim3(16, 86), 256, 0, stream>>>(x1_hi, x1_lo, wih1_hi, wih1_lo, b1, G, RTOT, 2048, 512);
    // 8. layer-2 scan (writes x2 region over dead x1p)
    hipMemsetAsync(hb, 0, 2*hsz*sizeof(float), stream);
    hipMemsetAsync(cb, 0, hsz*sizeof(float), stream);
    for (int s = 0; s < B_; ++s) {
        float* hin  = hb + (size_t)(s & 1) * hsz;
        float* hout = hb + (size_t)((s+1) & 1) * hsz;
        lstm_step_mfma_k<<<dim3(8, 11, 2), 256, 0, stream>>>(
            G, whh1_hi, whh1_lo, hin, hout, cb, x2, s);
    }
    // 9. pack x2 (into x1 region) + QKV/mh weights (into G tail slack; G dead)
    pack4_k<<<PACKGRID(1396736), 256, 0, stream>>>(x2, x2_hi, x2_lo, 1396736);
    pack4_k<<<PACKGRID(65536), 256, 0, stream>>>(Qw,  qw_hi, qw_lo, 65536);
    pack4_k<<<PACKGRID(65536), 256, 0, stream>>>(Kw,  kw_hi, kw_lo, 65536);
    pack4_k<<<PACKGRID(65536), 256, 0, stream>>>(Vw,  vw_hi, vw_lo, 65536);
    pack4_k<<<PACKGRID(65536), 256, 0, stream>>>(mhw, mw_hi, mw_lo, 65536);
    // 10. Q/K/V projections via MFMA
    gemm_bf_k<0><<<dim3(4, 86), 256, 0, stream>>>(x2_hi, x2_lo, qw_hi, qw_lo, Qb, qbuf, RTOT, 512, 512);
    gemm_bf_k<0><<<dim3(4, 86), 256, 0, stream>>>(x2_hi, x2_lo, kw_hi, kw_lo, Kb, kbuf, RTOT, 512, 512);
    gemm_bf_k<0><<<dim3(4, 86), 256, 0, stream>>>(x2_hi, x2_lo, vw_hi, vw_lo, Vb, vbuf, RTOT, 512, 512);
    // 11. attention in GRP-batch groups (pv writes cat = x1 region; x2p dead by then)
    for (int g = 0; g < B_/GRP; ++g) {
        scores_k <<<dim3(36, GRP, NH_), 256, 0, stream>>>(qbuf, kbuf, P, g);
        softmax_k<<<dim3(NH_*GRP*SP/4), 256, 0, stream>>>(P);
        pv_k     <<<dim3(6, GRP, NH_), 256, 0, stream>>>(P, vbuf, cat, g);
    }
    // 12. pack cat (into x2 region; x2 fp32 dead after step 9)
    pack4_k<<<PACKGRID(1396736), 256, 0, stream>>>(cat, cat_hi, cat_lo, 1396736);
    // 13. final linear + relu
    gemm_bf_k<1><<<dim3(4, 86), 256, 0, stream>>>(cat_hi, cat_lo, mw_hi, mw_lo, mhb, out, RTOT, 512, 512);
    #undef PACKGRID
}

// Round 3
// 1692.638 us; speedup vs baseline: 1.2890x; 1.0389x over previous
//
#include <hip/hip_runtime.h>
#include <math.h>

// Problem constants
#define B_    32
#define CIN   4
#define SLEN  2048
#define NF    256
#define HD    256          // LSTM hidden per direction
#define SP    341          // post conv+pool sequence length
#define RTOT  (B_*SP)      // 10912 rows
#define NH_   8
#define DH_   64
#define GRP   4            // batches per attention group
#define PSTR  344          // padded P row stride (16B-aligned)
#define HS    (SP*HD)      // 87296: per-dir h elems

typedef __attribute__((ext_vector_type(8))) short short8;
typedef __attribute__((ext_vector_type(4))) float floatx4;
typedef __attribute__((ext_vector_type(4))) unsigned short ushortx4;
typedef __attribute__((ext_vector_type(8))) unsigned short ushort8;

__device__ __forceinline__ float sigmoidf_(float x) { return 1.0f / (1.0f + expf(-x)); }

__device__ __forceinline__ unsigned short f2bf(float x) {
    unsigned int u = __float_as_uint(x);
    unsigned int r = (u + 0x7FFF + ((u >> 16) & 1)) >> 16;   // RNE
    return (unsigned short)r;
}
__device__ __forceinline__ float bf2f(unsigned short b) {
    return __uint_as_float(((unsigned int)b) << 16);
}

// ---------------------------------------------------------------------------
// Packed bf16 hi/lo "octet" layout: for a row of K fp32 values, the packed row
// has 2K ushorts: octet o (elems 8o..8o+7) occupies ushorts [16o..16o+7]=hi,
// [16o+8..16o+15]=lo.  One K-step of 32 elems = 128 contiguous bytes.
// ---------------------------------------------------------------------------

// Kernel 1: Conv1d(4->256,k13,pad6)+BN+ReLU+MaxPool1d(6) -> x0 packed
__global__ __launch_bounds__(256)
void conv_pool_k(const float* __restrict__ in, const float* __restrict__ cw,
                 const float* __restrict__ gamma, const float* __restrict__ beta,
                 unsigned short* __restrict__ x0p)
{
    const int b  = blockIdx.y;
    const int s0 = blockIdx.x * 16;
    const int co = threadIdx.x;
    __shared__ float ins[CIN][16*6 + 12];
    for (int idx = threadIdx.x; idx < CIN*108; idx += 256) {
        int ci = idx / 108, o = idx % 108;
        int pos = 6*s0 - 6 + o;
        ins[ci][o] = (pos >= 0 && pos < SLEN) ? in[(b*CIN + ci)*SLEN + pos] : 0.0f;
    }
    float wreg[52];
    {
        const float4* wp = (const float4*)(cw + co*52);
        #pragma unroll
        for (int j4 = 0; j4 < 13; ++j4) {
            float4 w4 = wp[j4];
            wreg[j4*4+0]=w4.x; wreg[j4*4+1]=w4.y; wreg[j4*4+2]=w4.z; wreg[j4*4+3]=w4.w;
        }
    }
    const float scale = gamma[co] * (1.0f / sqrtf(1.0f + 1e-5f));
    const float shift = beta[co];
    __syncthreads();
    for (int si = 0; si < 16; ++si) {
        int s = s0 + si;
        if (s >= SP) break;
        float win[CIN][18];
        #pragma unroll
        for (int ci = 0; ci < CIN; ++ci)
            #pragma unroll
            for (int o = 0; o < 18; ++o)
                win[ci][o] = ins[ci][6*si + o];
        float m = -1e30f;
        #pragma unroll
        for (int p6 = 0; p6 < 6; ++p6) {
            float acc = 0.0f;
            #pragma unroll
            for (int ci = 0; ci < CIN; ++ci)
                #pragma unroll
                for (int kk = 0; kk < 13; ++kk)
                    acc += win[ci][p6+kk] * wreg[ci*13+kk];
            float val = acc * scale + shift;
            val = fmaxf(val, 0.0f);
            m = fmaxf(m, val);
        }
        unsigned short hb_ = f2bf(m);
        unsigned short lb_ = f2bf(m - bf2f(hb_));
        size_t rb = (size_t)(b*SP + s)*512 + (size_t)(co >> 3)*16 + (co & 7);
        x0p[rb]     = hb_;
        x0p[rb + 8] = lb_;
    }
}

// Kernel 2a: fp32 -> separate hi/lo pack (for lstm Whh, layout unchanged)
__global__ __launch_bounds__(256)
void pack4_k(const float* __restrict__ W, unsigned short* __restrict__ hi,
             unsigned short* __restrict__ lo, int n4)
{
    int i = blockIdx.x * 256 + threadIdx.x;
    if (i >= n4) return;
    float4 x = *((const float4*)W + i);
    float v[4] = {x.x, x.y, x.z, x.w};
    ushortx4 h, l;
    #pragma unroll
    for (int e = 0; e < 4; ++e) {
        unsigned short hb = f2bf(v[e]);
        h[e] = hb;
        l[e] = f2bf(v[e] - bf2f(hb));
    }
    *((ushortx4*)hi + i) = h;
    *((ushortx4*)lo + i) = l;
}

// Kernel 2b: fp32 -> interleaved octet pack (8 elems/thread)
__global__ __launch_bounds__(256)
void pack8_k(const float* __restrict__ W, unsigned short* __restrict__ O, int n8)
{
    int i = blockIdx.x * 256 + threadIdx.x;
    if (i >= n8) return;
    const float4* wp = (const float4*)W + (size_t)i*2;
    float4 a = wp[0], b = wp[1];
    float v[8] = {a.x,a.y,a.z,a.w,b.x,b.y,b.z,b.w};
    ushort8 h, l;
    #pragma unroll
    for (int e = 0; e < 8; ++e) {
        unsigned short hb = f2bf(v[e]);
        h[e] = hb;
        l[e] = f2bf(v[e] - bf2f(hb));
    }
    *(ushort8*)(O + (size_t)i*16)     = h;
    *(ushort8*)(O + (size_t)i*16 + 8) = l;
}

// ---------------------------------------------------------------------------
// Kernel 3: split-bf16 MFMA GEMM, operands in packed octet layout.
// C[M,N] = act(A[M,K] @ Bw[N,K]^T + bias).  Tile 128x128, 4 waves, K-step 32.
// Reg-staged: coalesced short8 global loads; LDS write at chunk lj^(row&7)
// (per-row permutation -> conflict-free writes); frag ds_read_b128 applies the
// same XOR -> 2 lanes/bank (free).  LDS 32 KB.
// ---------------------------------------------------------------------------
template<int RELU>
__global__ __launch_bounds__(256)
void gemm_bf_k(const unsigned short* __restrict__ Ap, const unsigned short* __restrict__ Bp,
               const float* __restrict__ bias, float* __restrict__ C,
               int M, int N, int K)
{
    const int n0 = blockIdx.x * 128;
    const int m0 = blockIdx.y * 128;
    const int tid = threadIdx.x;
    const int lane = tid & 63;
    const int w = tid >> 6;
    const int wm = w >> 1, wn = w & 1;          // wave 2x2 over the 128x128 tile
    const int ln15 = lane & 15, lq = lane >> 4;
    const int l8 = lane >> 3, lj = lane & 7;    // staging: row-in-group, chunk
    const size_t rstr = 2*(size_t)K;            // packed row stride (ushorts)

    __shared__ unsigned short As[128*64];       // 128 rows x 128B (one K-step)
    __shared__ unsigned short Bs[128*64];

    floatx4 acc[4][4];
    #pragma unroll
    for (int i = 0; i < 4; ++i)
        #pragma unroll
        for (int j = 0; j < 4; ++j) acc[i][j] = (floatx4){0.f, 0.f, 0.f, 0.f};

    // per-thread staging rows (4 for A, 4 for B) and swizzled LDS positions
    int rloc[4];
    #pragma unroll
    for (int c = 0; c < 4; ++c) rloc[c] = w*32 + c*8 + l8;
    const int spos = lj ^ (l8 & 7);             // row&7 == l8 for these rows

    for (int k0 = 0; k0 < K; k0 += 32) {
        short8 va[4], vb[4];
        #pragma unroll
        for (int c = 0; c < 4; ++c) {
            int gra = m0 + rloc[c]; if (gra >= M) gra = M - 1;
            va[c] = *(const short8*)(Ap + (size_t)gra*rstr + k0*2 + lj*8);
            vb[c] = *(const short8*)(Bp + (size_t)(n0 + rloc[c])*rstr + k0*2 + lj*8);
        }
        __syncthreads();   // previous iteration's LDS reads complete
        #pragma unroll
        for (int c = 0; c < 4; ++c) {
            *(short8*)&As[rloc[c]*64 + spos*8] = va[c];
            *(short8*)&Bs[rloc[c]*64 + spos*8] = vb[c];
        }
        __syncthreads();

        short8 fa_h[4], fa_l[4], fb_h[4], fb_l[4];
        #pragma unroll
        for (int mt = 0; mt < 4; ++mt) {
            const int lr = wm*64 + mt*16 + ln15;
            fa_h[mt] = *(const short8*)&As[lr*64 + (((lq*2  ) ^ (lr&7))*8)];
            fa_l[mt] = *(const short8*)&As[lr*64 + (((lq*2+1) ^ (lr&7))*8)];
        }
        #pragma unroll
        for (int nt = 0; nt < 4; ++nt) {
            const int lr = wn*64 + nt*16 + ln15;
            fb_h[nt] = *(const short8*)&Bs[lr*64 + (((lq*2  ) ^ (lr&7))*8)];
            fb_l[nt] = *(const short8*)&Bs[lr*64 + (((lq*2+1) ^ (lr&7))*8)];
        }
        #pragma unroll
        for (int mt = 0; mt < 4; ++mt)
            #pragma unroll
            for (int nt = 0; nt < 4; ++nt) {
                acc[mt][nt] = __builtin_amdgcn_mfma_f32_16x16x32_bf16(fa_l[mt], fb_h[nt], acc[mt][nt], 0, 0, 0);
                acc[mt][nt] = __builtin_amdgcn_mfma_f32_16x16x32_bf16(fa_h[mt], fb_l[nt], acc[mt][nt], 0, 0, 0);
                acc[mt][nt] = __builtin_amdgcn_mfma_f32_16x16x32_bf16(fa_h[mt], fb_h[nt], acc[mt][nt], 0, 0, 0);
            }
    }

    // epilogue: D layout n=lane&15 (col), m=(lane>>4)*4+r (row)
    #pragma unroll
    for (int nt = 0; nt < 4; ++nt) {
        const int n = n0 + wn*64 + nt*16 + ln15;
        const float bv = bias[n];
        #pragma unroll
        for (int mt = 0; mt < 4; ++mt) {
            const int mbase = m0 + wm*64 + mt*16 + lq*4;
            #pragma unroll
            for (int r = 0; r < 4; ++r) {
                int m = mbase + r;
                if (m < M) {
                    float val = acc[mt][nt][r] + bv;
                    if (RELU) val = fmaxf(val, 0.0f);
                    C[(size_t)m*N + n] = val;
                }
            }
        }
    }
}

// ---------------------------------------------------------------------------
// Kernel 3b: one LSTM step via split-bf16 MFMA. x_out written PACKED.
// ---------------------------------------------------------------------------
__global__ __launch_bounds__(256)
void lstm_step_mfma_k(const float* __restrict__ G,              // [32*341][2048]
                      const unsigned short* __restrict__ Whi,   // [2][1024][256]
                      const unsigned short* __restrict__ Wlo,
                      const float* __restrict__ h_in,           // [2][341][256] fp32
                      float* __restrict__ h_out,
                      float* __restrict__ c_st,                 // [2][341][256]
                      unsigned short* __restrict__ x_out,       // [32*341] packed rows of 512
                      int s)
{
    const int j0 = blockIdx.x * 32;
    const int m0 = blockIdx.y * 32;
    const int d  = blockIdx.z;
    const int t_in = d ? (B_ - 1 - s) : s;
    const int tid = threadIdx.x;
    const int w = tid >> 6, lane = tid & 63;
    const int mhalf = w & 1, gpair = w >> 1;
    const int ln15 = lane & 15, lq = lane >> 4;

    __shared__ float Csh[32][132];

    int am = m0 + mhalf*16 + ln15; if (am > SP-1) am = SP-1;   // A row (clamped)
    const int akoff = lq * 8;
    const float* hA = h_in + (size_t)d*HS + (size_t)am*HD;

    const unsigned short* WhiD = Whi + (size_t)d*1024*256;
    const unsigned short* WloD = Wlo + (size_t)d*1024*256;
    int nrow[4];   // Whh row (output col) per n-subtile
    #pragma unroll
    for (int t = 0; t < 4; ++t)
        nrow[t] = (gpair*2 + (t>>1))*256 + j0 + (t&1)*16 + ln15;

    floatx4 acc[4];
    #pragma unroll
    for (int t = 0; t < 4; ++t) acc[t] = (floatx4){0.f, 0.f, 0.f, 0.f};

    #pragma unroll
    for (int kk = 0; kk < 8; ++kk) {
        const int ko = kk*32 + akoff;
        float4 v0 = *(const float4*)(hA + ko);
        float4 v1 = *(const float4*)(hA + ko + 4);
        float vv[8] = {v0.x, v0.y, v0.z, v0.w, v1.x, v1.y, v1.z, v1.w};
        short8 ahi, alo;
        #pragma unroll
        for (int e = 0; e < 8; ++e) {
            unsigned short hb16 = f2bf(vv[e]);
            ahi[e] = (short)hb16;
            alo[e] = (short)f2bf(vv[e] - bf2f(hb16));
        }
        #pragma unroll
        for (int t = 0; t < 4; ++t) {
            short8 bhi = *(const short8*)(WhiD + (size_t)nrow[t]*HD + ko);
            short8 blo = *(const short8*)(WloD + (size_t)nrow[t]*HD + ko);
            acc[t] = __builtin_amdgcn_mfma_f32_16x16x32_bf16(alo, bhi, acc[t], 0, 0, 0);
            acc[t] = __builtin_amdgcn_mfma_f32_16x16x32_bf16(ahi, blo, acc[t], 0, 0, 0);
            acc[t] = __builtin_amdgcn_mfma_f32_16x16x32_bf16(ahi, bhi, acc[t], 0, 0, 0);
        }
    }

    // dump C fragments to LDS (D: col=lane&15, row=lq*4+reg)
    #pragma unroll
    for (int t = 0; t < 4; ++t) {
        int col = gpair*64 + (t>>1)*32 + (t&1)*16 + ln15;
        int rb  = mhalf*16 + lq*4;
        #pragma unroll
        for (int r = 0; r < 4; ++r)
            Csh[rb + r][col] = acc[t][r];
    }
    __syncthreads();

    const int emloc = tid >> 3;           // 0..31 local row
    const int ej4   = (tid & 7) * 4;      // 0..28 local col (x4)
    const int em    = m0 + emloc;
    if (em < SP) {
        size_t gb = ((size_t)t_in*SP + em)*2048 + (size_t)d*1024 + j0 + ej4;
        float4 gi4 = *(const float4*)&G[gb];
        float4 gf4 = *(const float4*)&G[gb + 256];
        float4 gg4 = *(const float4*)&G[gb + 512];
        float4 go4 = *(const float4*)&G[gb + 768];
        size_t cbase = ((size_t)d*SP + em)*HD + j0 + ej4;
        float4 cold = *(float4*)&c_st[cbase];
        float hv[4];
        #pragma unroll
        for (int e = 0; e < 4; ++e) {
            float gi = Csh[emloc][     ej4+e] + (&gi4.x)[e];
            float gf = Csh[emloc][32 + ej4+e] + (&gf4.x)[e];
            float gg = Csh[emloc][64 + ej4+e] + (&gg4.x)[e];
            float go = Csh[emloc][96 + ej4+e] + (&go4.x)[e];
            float cn = sigmoidf_(gf)*(&cold.x)[e] + sigmoidf_(gi)*tanhf(gg);
            (&cold.x)[e] = cn;
            hv[e] = sigmoidf_(go)*tanhf(cn);
        }
        *(float4*)&c_st[cbase] = cold;
        float4 ho; ho.x = hv[0]; ho.y = hv[1]; ho.z = hv[2]; ho.w = hv[3];
        *(float4*)&h_out[cbase] = ho;
        // packed x_out write
        const int colg = d*HD + j0 + ej4;
        size_t xb = ((size_t)t_in*SP + em)*1024 + (size_t)(colg >> 3)*16 + (colg & 7);
        ushortx4 xh, xl;
        #pragma unroll
        for (int e = 0; e < 4; ++e) {
            unsigned short hb16 = f2bf(hv[e]);
            xh[e] = hb16;
            xl[e] = f2bf(hv[e] - bf2f(hb16));
        }
        *(ushortx4*)&x_out[xb]     = xh;
        *(ushortx4*)&x_out[xb + 8] = xl;
    }
}

// ---------------------------------------------------------------------------
// Kernel 4a: scores tile (64x64), RPE analytic.
// ---------------------------------------------------------------------------
__global__ __launch_bounds__(256)
void scores_k(const float* __restrict__ q, const float* __restrict__ k,
              float* __restrict__ P, int g)
{
    const int h = blockIdx.z, bl = blockIdx.y, bg = g*GRP + bl;
    const int q0 = (blockIdx.x / 6) * 64;
    const int k0 = (blockIdx.x % 6) * 64;
    const int tid = threadIdx.x;
    __shared__ float qs[64][68];
    __shared__ float ks[64][68];
    {
        int jr = tid >> 2, c16 = (tid & 3) * 16;
        int qq = q0 + jr; if (qq > SP-1) qq = SP-1;
        int kr = k0 + jr; if (kr > SP-1) kr = SP-1;
        const float* qp = &q[((size_t)bg*SP + qq)*512 + h*64 + c16];
        const float* kp = &k[((size_t)bg*SP + kr)*512 + h*64 + c16];
        #pragma unroll
        for (int u = 0; u < 4; ++u) {
            *(float4*)&qs[jr][c16 + u*4] = *(const float4*)(qp + u*4);
            *(float4*)&ks[jr][c16 + u*4] = *(const float4*)(kp + u*4);
        }
    }
    __syncthreads();
    const int tx = tid & 15, ty = tid >> 4;
    float acc[4][4];
    #pragma unroll
    for (int i = 0; i < 4; ++i)
        #pragma unroll
        for (int j = 0; j < 4; ++j) acc[i][j] = 0.0f;
    for (int d4 = 0; d4 < 64; d4 += 4) {
        float4 a[4], b[4];
        #pragma unroll
        for (int i = 0; i < 4; ++i) a[i] = *(const float4*)&qs[ty + 16*i][d4];
        #pragma unroll
        for (int j = 0; j < 4; ++j) b[j] = *(const float4*)&ks[tx + 16*j][d4];
        #pragma unroll
        for (int i = 0; i < 4; ++i)
            #pragma unroll
            for (int j = 0; j < 4; ++j)
                acc[i][j] += a[i].x*b[j].x + a[i].y*b[j].y + a[i].z*b[j].z + a[i].w*b[j].w;
    }
    #pragma unroll
    for (int i = 0; i < 4; ++i) {
        int qq = q0 + ty + 16*i;
        if (qq >= SP) continue;
        int r0 = 6*qq - 1; if (r0 < 0) r0 = 0;
        int r1 = 6*qq + 7; if (r1 > SLEN-1) r1 = SLEN-1;
        size_t rowb = ((size_t)(h*GRP + bl)*SP + qq) * PSTR;
        #pragma unroll
        for (int j = 0; j < 4; ++j) {
            int kk = k0 + tx + 16*j;
            if (kk >= SP) continue;
            int c0 = 6*kk - 1; if (c0 < 0) c0 = 0;
            int c1 = 6*kk + 7;
            int dd1 = c1 - r0; if (dd1 < 0) dd1 = -dd1;
            int dd2 = r1 - c0; if (dd2 < 0) dd2 = -dd2;
            int den = dd1 > dd2 ? dd1 : dd2;
            P[rowb + kk] = (acc[i][j] * 0.125f) * 2047.0f / (float)den;
        }
    }
}

// ---------------------------------------------------------------------------
// Kernel 4b: row softmax in place.
// ---------------------------------------------------------------------------
__global__ __launch_bounds__(256)
void softmax_k(float* __restrict__ P)
{
    const int tid = threadIdx.x;
    const int row = blockIdx.x * 4 + (tid >> 6);
    const int lane = tid & 63;
    float* rp = P + (size_t)row * PSTR;
    float v[6];
    float m = -1e30f;
    #pragma unroll
    for (int i = 0; i < 6; ++i) {
        int col = lane + 64*i;
        v[i] = (col < SP) ? rp[col] : -1e30f;
        m = fmaxf(m, v[i]);
    }
    #pragma unroll
    for (int o = 1; o < 64; o <<= 1) m = fmaxf(m, __shfl_xor(m, o, 64));
    float s = 0.0f;
    #pragma unroll
    for (int i = 0; i < 6; ++i) {
        v[i] = expf(v[i] - m);
        s += v[i];
    }
    #pragma unroll
    for (int o = 1; o < 64; o <<= 1) s += __shfl_xor(s, o, 64);
    float inv = 1.0f / s;
    #pragma unroll
    for (int i = 0; i < 6; ++i) {
        int col = lane + 64*i;
        if (col < SP) rp[col] = v[i] * inv;
    }
}

// ---------------------------------------------------------------------------
// Kernel 4c: out = relu(P @ V), K=SP in 6x64 chunks. cat written PACKED.
// ---------------------------------------------------------------------------
__global__ __launch_bounds__(256)
void pv_k(const float* __restrict__ P, const float* __restrict__ v,
          unsigned short* __restrict__ catp, int g)
{
    const int h = blockIdx.z, bl = blockIdx.y, bg = g*GRP + bl;
    const int q0 = blockIdx.x * 64;
    const int tid = threadIdx.x;
    __shared__ float ps[64][68];
    __shared__ float vs[64][68];
    const int tx = tid & 15, ty = tid >> 4;
    float acc[4][4];
    #pragma unroll
    for (int i = 0; i < 4; ++i)
        #pragma unroll
        for (int j = 0; j < 4; ++j) acc[i][j] = 0.0f;

    for (int kc = 0; kc < 6; ++kc) {
        const int kk0 = kc * 64;
        {
            int jr = tid >> 2, c16 = (tid & 3) * 16;
            int qq = q0 + jr; if (qq > SP-1) qq = SP-1;
            const float* pp = P + ((size_t)(h*GRP + bl)*SP + qq)*PSTR + kk0 + c16;
            #pragma unroll
            for (int u = 0; u < 4; ++u) {
                float4 w = *(const float4*)(pp + u*4);
                int klb = c16 + u*4;
                float vals[4] = {w.x, w.y, w.z, w.w};
                #pragma unroll
                for (int e = 0; e < 4; ++e)
                    ps[klb + e][jr] = (kk0 + klb + e < SP) ? vals[e] : 0.0f;
            }
        }
        {
            int jr = tid >> 2, c16 = (tid & 3) * 16;
            int kr = kk0 + jr; if (kr > SP-1) kr = SP-1;
            const float* vp = &v[((size_t)bg*SP + kr)*512 + h*64 + c16];
            #pragma unroll
            for (int u = 0; u < 4; ++u)
                *(float4*)&vs[jr][c16 + u*4] = *(const float4*)(vp + u*4);
        }
        __syncthreads();
        for (int kk = 0; kk < 64; ++kk) {
            float4 a4 = *(const float4*)&ps[kk][ty*4];
            float4 b4 = *(const float4*)&vs[kk][tx*4];
            float av[4] = {a4.x, a4.y, a4.z, a4.w};
            float bv[4] = {b4.x, b4.y, b4.z, b4.w};
            #pragma unroll
            for (int i = 0; i < 4; ++i)
                #pragma unroll
                for (int j = 0; j < 4; ++j)
                    acc[i][j] += av[i] * bv[j];
        }
        __syncthreads();
    }
    #pragma unroll
    for (int i = 0; i < 4; ++i) {
        int qq = q0 + ty*4 + i;
        if (qq >= SP) continue;
        float r[4];
        r[0] = fmaxf(acc[i][0], 0.0f);
        r[1] = fmaxf(acc[i][1], 0.0f);
        r[2] = fmaxf(acc[i][2], 0.0f);
        r[3] = fmaxf(acc[i][3], 0.0f);
        const int colg = h*64 + tx*4;
        size_t xb = ((size_t)bg*SP + qq)*1024 + (size_t)(colg >> 3)*16 + (colg & 7);
        ushortx4 xh, xl;
        #pragma unroll
        for (int e = 0; e < 4; ++e) {
            unsigned short hb16 = f2bf(r[e]);
            xh[e] = hb16;
            xl[e] = f2bf(r[e] - bf2f(hb16));
        }
        *(ushortx4*)&catp[xb]     = xh;
        *(ushortx4*)&catp[xb + 8] = xl;
    }
}

// ---------------------------------------------------------------------------
extern "C" void kernel_launch(void* const* d_in, const int* in_sizes, int n_in,
                              void* d_out, int out_size, void* d_ws, size_t ws_size,
                              hipStream_t stream)
{
    (void)in_sizes; (void)n_in; (void)out_size; (void)ws_size;
    const float* in    = (const float*)d_in[0];
    const float* cw    = (const float*)d_in[1];
    const float* gamma = (const float*)d_in[2];
    const float* beta  = (const float*)d_in[3];
    const float* Wih0  = (const float*)d_in[4];
    const float* Whh0  = (const float*)d_in[5];
    const float* b0    = (const float*)d_in[6];
    const float* Wih1  = (const float*)d_in[7];
    const float* Whh1  = (const float*)d_in[8];
    const float* b1    = (const float*)d_in[9];
    const float* Qw    = (const float*)d_in[10];
    const float* Qb    = (const float*)d_in[11];
    const float* Kw    = (const float*)d_in[12];
    const float* Kb    = (const float*)d_in[13];
    const float* Vw    = (const float*)d_in[14];
    const float* Vb    = (const float*)d_in[15];
    const float* mhw   = (const float*)d_in[16];
    const float* mhb   = (const float*)d_in[17];
    float* out = (float*)d_out;

    // workspace arena (floats). Same region map as before.
    float* x0 = (float*)d_ws;                                   //  2,793,472 f
    float* G  = x0 + (size_t)RTOT*NF;                           // 22,347,776 f
    float* x1 = G  + (size_t)RTOT*2048;                         //  5,586,944 f
    float* x2 = x1 + (size_t)RTOT*512;                          //  5,586,944 f
    float* hb = x2 + (size_t)RTOT*512;                          //    349,184 f
    float* cb = hb + (size_t)2*2*SP*HD;                         //    174,592 f

    float* qbuf = G;
    float* kbuf = G + (size_t)RTOT*512;
    float* vbuf = G + (size_t)2*RTOT*512;
    float* P    = G + (size_t)3*RTOT*512;
    const size_t hsz = (size_t)2*SP*HD;

    // ---- packed-buffer aliases (each placed in a region dead at time of use) ----
    // x0 region: x0p (conv output, packed in place; exact fit).
    unsigned short* x0p = (unsigned short*)x0;
    // After gemm1 (x0p dead): whh1 hi/lo live in x0 region through scan2.
    unsigned short* whh1_hi = (unsigned short*)x0;                         // 524,288 ush
    unsigned short* whh1_lo = whh1_hi + (size_t)524288;                    // ends 524,288 f
    // x2 region until scan2: wih0_p, wih1_p, whh0 hi/lo.
    unsigned short* wih0_p  = (unsigned short*)x2;                         // 1,048,576 ush
    unsigned short* wih1_p  = wih0_p + (size_t)1048576;                    // 2,097,152 ush
    unsigned short* whh0_hi = wih1_p + (size_t)2097152;                    // 524,288 ush
    unsigned short* whh0_lo = whh0_hi + (size_t)524288;                    // ends 2,097,152 f < 5,586,944
    // x1 region: x1p (scan1 packed output, exact fit); later catp (pv output).
    unsigned short* x1p  = (unsigned short*)x1;
    unsigned short* catp = (unsigned short*)x1;
    // x2 region after scan2: x2p (scan2 packed output, exact fit).
    unsigned short* x2p = (unsigned short*)x2;
    // G tail slack after P (G-as-gates dead after scan2): QKV/mh weight packs.
    float* gslack = P + (size_t)NH_*GRP*SP*PSTR;                           // 1,833,216 f slack
    unsigned short* qw_p = (unsigned short*)gslack;                        // 524,288 ush each
    unsigned short* kw_p = qw_p + (size_t)524288;
    unsigned short* vw_p = kw_p + (size_t)524288;
    unsigned short* mw_p = vw_p + (size_t)524288;                          // 1,048,576 f used

    #define PACKGRID(n) dim3(((n) + 255) / 256)

    // 1. conv+bn+relu+pool -> x0p (packed)
    conv_pool_k<<<dim3(22, B_), 256, 0, stream>>>(in, cw, gamma, beta, x0p);
    // 2. pack Wih0 (octet) into x2 region
    pack8_k<<<PACKGRID(65536), 256, 0, stream>>>(Wih0, wih0_p, 65536);
    // 3. layer-1 input gates: G = x0 @ Wih0^T + b0   (K=256)
    gemm_bf_k<0><<<dim3(16, 86), 256, 0, stream>>>(x0p, wih0_p, b0, G, RTOT, 2048, 256);
    // 4. pack Whh0 (x2 tail), Whh1 (x0 region, dead after gemm1), Wih1 (x2)
    pack4_k<<<PACKGRID(131072), 256, 0, stream>>>(Whh0, whh0_hi, whh0_lo, 131072);
    pack4_k<<<PACKGRID(131072), 256, 0, stream>>>(Whh1, whh1_hi, whh1_lo, 131072);
    pack8_k<<<PACKGRID(131072), 256, 0, stream>>>(Wih1, wih1_p, 131072);
    // 5. layer-1 scan -> x1p (packed)
    hipMemsetAsync(hb, 0, 2*hsz*sizeof(float), stream);
    hipMemsetAsync(cb, 0, hsz*sizeof(float), stream);
    for (int s = 0; s < B_; ++s) {
        float* hin  = hb + (size_t)(s & 1) * hsz;
        float* hout = hb + (size_t)((s+1) & 1) * hsz;
        lstm_step_mfma_k<<<dim3(8, 11, 2), 256, 0, stream>>>(
            G, whh0_hi, whh0_lo, hin, hout, cb, x1p, s);
    }
    // 6. layer-2 input gates: G = x1 @ Wih1^T + b1   (K=512)
    gemm_bf_k<0><<<dim3(16, 86), 256, 0, stream>>>(x1p, wih1_p, b1, G, RTOT, 2048, 512);
    // 7. layer-2 scan -> x2p (packed; overwrites x2-region weight packs, all dead)
    hipMemsetAsync(hb, 0, 2*hsz*sizeof(float), stream);
    hipMemsetAsync(cb, 0, hsz*sizeof(float), stream);
    for (int s = 0; s < B_; ++s) {
        float* hin  = hb + (size_t)(s & 1) * hsz;
        float* hout = hb + (size_t)((s+1) & 1) * hsz;
        lstm_step_mfma_k<<<dim3(8, 11, 2), 256, 0, stream>>>(
            G, whh1_hi, whh1_lo, hin, hout, cb, x2p, s);
    }
    // 8. pack QKV/mh weights into G tail slack (G-as-gates dead)
    pack8_k<<<PACKGRID(32768), 256, 0, stream>>>(Qw,  qw_p, 32768);
    pack8_k<<<PACKGRID(32768), 256, 0, stream>>>(Kw,  kw_p, 32768);
    pack8_k<<<PACKGRID(32768), 256, 0, stream>>>(Vw,  vw_p, 32768);
    pack8_k<<<PACKGRID(32768), 256, 0, stream>>>(mhw, mw_p, 32768);
    // 9. Q/K/V projections (fp32 outputs into G region)
    gemm_bf_k<0><<<dim3(4, 86), 256, 0, stream>>>(x2p, qw_p, Qb, qbuf, RTOT, 512, 512);
    gemm_bf_k<0><<<dim3(4, 86), 256, 0, stream>>>(x2p, kw_p, Kb, kbuf, RTOT, 512, 512);
    gemm_bf_k<0><<<dim3(4, 86), 256, 0, stream>>>(x2p, vw_p, Vb, vbuf, RTOT, 512, 512);
    // 10. attention in GRP-batch groups; pv writes catp (x1 region, packed)
    for (int g = 0; g < B_/GRP; ++g) {
        scores_k <<<dim3(36, GRP, NH_), 256, 0, stream>>>(qbuf, kbuf, P, g);
        softmax_k<<<dim3(NH_*GRP*SP/4), 256, 0, stream>>>(P);
        pv_k     <<<dim3(6, GRP, NH_), 256, 0, stream>>>(P, vbuf, catp, g);
    }
    // 11. final linear + relu
    gemm_bf_k<1><<<dim3(4, 86), 256, 0, stream>>>(catp, mw_p, mhb, out, RTOT, 512, 512);
    #undef PACKGRID
}